// Round 6
// baseline (1018.690 us; speedup 1.0000x reference)
//
#include <hip/hip_runtime.h>
#include <math.h>

#define BB 16
#define TT 16
#define KK 4
#define VV 10003
#define DD 256
#define CC 64
#define RPB 4           // rows per k_gemm block
#define VT  1280        // v-span per block: 1024 (4/thread packed) + 256 (1/thread)
#define NVT 8           // v-tiles; 8 tiles -> tile == bid%8 == XCD (stable)
#define VP 10016        // padded row stride for logits scratch
#define FNEG (-1e30f)

typedef float f32x4 __attribute__((ext_vector_type(4)));
// 4-float vector with only 4-byte alignment guaranteed (Wv row stride 10003
// floats is odd, so d-slices of a column group are not 16B-aligned)
typedef float f32x4u __attribute__((ext_vector_type(4), aligned(4)));

// ---------- top-4, branch-free named-scalar version (no runtime indexing,
// stays in VGPRs; list kept sorted desc under strict total order) ----------
struct L4 { float v0, v1, v2, v3; int i0, i1, i2, i3; };

__device__ __forceinline__ void l4_init(L4 &l) {
  l.v0 = l.v1 = l.v2 = l.v3 = FNEG;
  l.i0 = l.i1 = l.i2 = l.i3 = 0x7fffffff;
}
__device__ __forceinline__ bool better(float v, int ix, float v2, int ix2) {
  return (v > v2) || (v == v2 && ix < ix2);
}
__device__ __forceinline__ void l4_insert(L4 &l, float v, int ix) {
  const bool c0 = better(v, ix, l.v0, l.i0);
  const bool c1 = better(v, ix, l.v1, l.i1);
  const bool c2 = better(v, ix, l.v2, l.i2);
  const bool c3 = better(v, ix, l.v3, l.i3);
  // update back-to-front with OLD values (sorted => c0=>c1=>c2=>c3)
  l.v3 = c3 ? (c2 ? l.v2 : v) : l.v3;  l.i3 = c3 ? (c2 ? l.i2 : ix) : l.i3;
  l.v2 = c2 ? (c1 ? l.v1 : v) : l.v2;  l.i2 = c2 ? (c1 ? l.i1 : ix) : l.i2;
  l.v1 = c1 ? (c0 ? l.v0 : v) : l.v1;  l.i1 = c1 ? (c0 ? l.i0 : ix) : l.i1;
  l.v0 = c0 ? v : l.v0;                l.i0 = c0 ? ix : l.i0;
}
__device__ __forceinline__ void l4_merge(L4 &a, const L4 &b) {
  l4_insert(a, b.v0, b.i0);
  l4_insert(a, b.v1, b.i1);
  l4_insert(a, b.v2, b.i2);
  l4_insert(a, b.v3, b.i3);
}
__device__ __forceinline__ L4 l4_shfl_xor(const L4 &a, int off) {
  L4 o;
  o.v0 = __shfl_xor(a.v0, off); o.i0 = __shfl_xor(a.i0, off);
  o.v1 = __shfl_xor(a.v1, off); o.i1 = __shfl_xor(a.i1, off);
  o.v2 = __shfl_xor(a.v2, off); o.i2 = __shfl_xor(a.i2, off);
  o.v3 = __shfl_xor(a.v3, off); o.i3 = __shfl_xor(a.i3, off);
  return o;
}

// ---------- kernel 1: logits GEMM + fused beam(step-1) recompute ----------
// Dispatch-count reduction without fences (R4 lesson): k_beam's selection is
// a tiny pure function of (topP, topI, prob) from the PREVIOUS dispatches, so
// every gemm block recomputes it redundantly (deterministic shfl networks ->
// identical results everywhere); block 0 persists chainOut/probOut for the
// NEXT dispatch (coherence via kernel boundary). k_init absorbed: step-0
// tokens come straight from loc_tar. GEMM core is byte-identical to the
// proven R3/R5 kernel (h = E[c]+zs[b], one f32 acc per (row,col), fmaf
// strictly ascending d, bias after).
__global__ __launch_bounds__(256, 1)
void k_gemm(const float* __restrict__ E, const float* __restrict__ zs,
            const float* __restrict__ Wv, const float* __restrict__ bv,
            const int* __restrict__ loc_tar,
            const float* __restrict__ topP, const int* __restrict__ topI,
            const float* __restrict__ probIn, const int* __restrict__ chainIn,
            float* __restrict__ probOut, int* __restrict__ chainOut,
            float* __restrict__ Lg, int step, int N, int Mshift) {
  __shared__ __align__(16) float xs[RPB * DD];   // 4 KB (h rows, broadcast-read)
  __shared__ int cs[RPB];
  __shared__ int selSrc[BB][8];
  __shared__ int selTok[BB][8];
  __shared__ float prS[BB * 8];

  const int t = threadIdx.x;
  const int tile = blockIdx.x % NVT;          // tile == XCD (stable mapping)
  const int n0 = (blockIdx.x / NVT) * RPB;    // N is a multiple of RPB
  const int v0 = tile * VT;

  const int v4 = v0 + (t << 2);               // packed group; max 9983 < VV
  const int v1 = v0 + 1024 + t;               // extra column
  const int v1ok = (v1 < VV);
  const int v1c = v1ok ? v1 : (VV - 1);

  // ---- fused beam(step-1) recompute (exact replica of k_beam) ----
  if (step >= 2) {
    const int M = (step == 2) ? 4 : 8;        // beam(s=step-1): M=(s==1)?4:8
    const int nc = M * 4;
    const int c = t & 31;
    const int bh = t >> 5;                    // 0..7
    for (int h = 0; h < 2; ++h) {
      const int b = bh + h * 8;
      float act;
      if (c < nc) {
        int mi = c >> 2, k = c & 3;
        act = probIn[b * 8 + mi] * topP[(b * M + mi) * 4 + k];
      } else {
        act = -INFINITY;
      }
      for (int j = 0; j < 8; ++j) {
        float rv = act; int ri = c;
#pragma unroll
        for (int off = 1; off < 32; off <<= 1) {
          float v2 = __shfl_xor(rv, off, 32);
          int   i2 = __shfl_xor(ri, off, 32);
          if (v2 > rv || (v2 == rv && i2 < ri)) { rv = v2; ri = i2; }
        }
        if (c == ri) act = -INFINITY;          // mark used
        if (c == 0) {
          int mi = ri >> 2, k = ri & 3;
          int src = b * M + mi;
          int tok = topI[src * 4 + k]; if ((unsigned)tok >= VV) tok = 0;
          selSrc[b][j] = src;
          selTok[b][j] = tok;
          prS[b * 8 + j] = rv;
        }
      }
    }
    __syncthreads();
  }

  if (t < RPB) {
    int n = n0 + t;
    int ctok;
    if (step == 0)      ctok = loc_tar[n * TT];                 // init chain col 0
    else if (step == 1) ctok = topI[(n >> 2) * 4 + (n & 3)];    // beam(0) token
    else                ctok = selTok[n >> 3][n & 7];           // beam(s>=1) token
    if ((unsigned)ctok >= VV) ctok = 0;    // defensive
    cs[t] = ctok;
  }
  __syncthreads();

  // writer block persists chain/prob for the NEXT gemm dispatch
  if (blockIdx.x == 0 && step >= 1) {
    if (step == 1) {                         // beam(0): 16 -> 64 rows
      for (int e = t; e < BB * KK * TT; e += 256) {
        int dst = e >> 4, q = e & 15;
        int bb = dst >> 2, kk = dst & 3;
        int val;
        if (q == 1) { int tok = topI[bb * 4 + kk]; if ((unsigned)tok >= VV) tok = 0; val = tok; }
        else if (q == 0) val = loc_tar[bb * TT];
        else val = 0;
        chainOut[dst * TT + q] = val;
      }
      if (t < BB * KK) {
        int bb = t >> 2, kk = t & 3;
        probOut[bb * 8 + kk] = topP[bb * 4 + kk];
      }
    } else {                                 // beam(s>=1): -> 128 rows
      for (int e = t; e < BB * 8 * TT; e += 256) {
        int dst = e >> 4, q = e & 15;
        int bb = dst >> 3, j = dst & 7;
        int src = selSrc[bb][j];
        int val = (q == step) ? selTok[bb][j] : chainIn[src * TT + q];
        chainOut[dst * TT + q] = val;
      }
      if (t < BB * 8) probOut[t] = prS[t];
    }
  }

  // stage xs rows: h = E[c] + zs[b]  (single f32 add, np order)
  for (int e = t; e < RPB * DD; e += 256) {
    int r = e >> 8, d = e & 255;
    int n = n0 + r;
    int b = n >> Mshift;
    xs[e] = E[cs[r] * DD + d] + zs[b * DD + d];
  }
  __syncthreads();

  const float* w4p = Wv + v4;
  const float* w1p = Wv + v1c;

  float acc4[RPB][4];
  float acc1[RPB];
#pragma unroll
  for (int r = 0; r < RPB; ++r) {
    acc1[r] = 0.f;
#pragma unroll
    for (int j = 0; j < 4; ++j) acc4[r][j] = 0.f;
  }

  // 8-d groups, double-buffered (A/B): W from global, h from LDS
  f32x4u w4A[8], w4B[8];
  float  w1A[8], w1B[8];
  f32x4  h0A[RPB], h1A[RPB], h0B[RPB], h1B[RPB];

#pragma unroll
  for (int u = 0; u < 8; ++u) {
    w4A[u] = *(const f32x4u*)(w4p + (size_t)u * VV);
    w1A[u] = w1p[(size_t)u * VV];
  }
#pragma unroll
  for (int r = 0; r < RPB; ++r) {
    h0A[r] = *(const f32x4*)(xs + r * DD);
    h1A[r] = *(const f32x4*)(xs + r * DD + 4);
  }

  for (int d0 = 0; d0 < DD; d0 += 16) {
    const int dB = d0 + 8;
#pragma unroll
    for (int u = 0; u < 8; ++u) {
      w4B[u] = *(const f32x4u*)(w4p + (size_t)(dB + u) * VV);
      w1B[u] = w1p[(size_t)(dB + u) * VV];
    }
#pragma unroll
    for (int r = 0; r < RPB; ++r) {
      h0B[r] = *(const f32x4*)(xs + r * DD + dB);
      h1B[r] = *(const f32x4*)(xs + r * DD + dB + 4);
    }

#pragma unroll
    for (int u = 0; u < 8; ++u) {          // d ascending within group
#pragma unroll
      for (int r = 0; r < RPB; ++r) {
        const float hv = (u < 4) ? h0A[r][u] : h1A[r][u - 4];
#pragma unroll
        for (int j = 0; j < 4; ++j) acc4[r][j] = fmaf(hv, w4A[u][j], acc4[r][j]);
        acc1[r] = fmaf(hv, w1A[u], acc1[r]);
      }
    }

    const int dA = (d0 + 16 < DD) ? (d0 + 16) : 0;   // dummy reload last iter
#pragma unroll
    for (int u = 0; u < 8; ++u) {
      w4A[u] = *(const f32x4u*)(w4p + (size_t)(dA + u) * VV);
      w1A[u] = w1p[(size_t)(dA + u) * VV];
    }
#pragma unroll
    for (int r = 0; r < RPB; ++r) {
      h0A[r] = *(const f32x4*)(xs + r * DD + dA);
      h1A[r] = *(const f32x4*)(xs + r * DD + dA + 4);
    }

#pragma unroll
    for (int u = 0; u < 8; ++u) {
#pragma unroll
      for (int r = 0; r < RPB; ++r) {
        const float hv = (u < 4) ? h0B[r][u] : h1B[r][u - 4];
#pragma unroll
        for (int j = 0; j < 4; ++j) acc4[r][j] = fmaf(hv, w4B[u][j], acc4[r][j]);
        acc1[r] = fmaf(hv, w1B[u], acc1[r]);
      }
    }
  }

  // epilogue: bias after gemm (np), vectorized store for the packed group
  const f32x4u bv4 = *(const f32x4u*)(bv + v4);
#pragma unroll
  for (int r = 0; r < RPB; ++r) {
    f32x4 o;
#pragma unroll
    for (int j = 0; j < 4; ++j) o[j] = acc4[r][j] + bv4[j];
    *(f32x4*)(Lg + (size_t)(n0 + r) * VP + v4) = o;   // 16B aligned
  }
  if (v1ok) {
    const float bvv = bv[v1];
#pragma unroll
    for (int r = 0; r < RPB; ++r)
      Lg[(size_t)(n0 + r) * VP + v1] = acc1[r] + bvv;
  }
}

// ---------- kernel 2: np-exact max/top4/pairwise-lse, 3 barriers ----------
// Leaf phase now residue-parallel across ALL 16 waves (was 1 wave, 15 idle):
// 8 lanes per leaf, lane j owns accumulator r_j (indices j, j+8, ... ascending
// — same order as the scalar base case), combined via shfl in the exact
// ((r0+r1)+(r2+r3))+((r4+r5)+(r6+r7)) order, lane-0 serial tail. Bit-exact.
__global__ __launch_bounds__(1024)
void k_red(const float* __restrict__ Lg, float* __restrict__ topP,
           int* __restrict__ topI) {
  __shared__ __align__(16) float row[VV];   // exp'd values (pairwise sums)
  __shared__ float wmax[16];
  __shared__ float wv4[16 * 4];
  __shared__ int   wi4[16 * 4];
  __shared__ float leafS[128];

  const int n = blockIdx.x;
  const int t = threadIdx.x;
  const int lane = t & 63;
  const int wid = t >> 6;
  const float* grow = Lg + (size_t)n * VP;

  // ---- load: 3 x4 groups per thread (4t, 4096+4t, 8192+4t) ----
  const int va = t << 2;            // 0..4095, always valid
  const int vb = 4096 + (t << 2);   // 4096..8191, always valid
  const int vc = 8192 + (t << 2);   // valid fully for t<=451; partial t=452
  f32x4 xa = *(const f32x4*)(grow + va);
  f32x4 xb = *(const f32x4*)(grow + vb);
  f32x4 xc;
  const bool cfull = (vc + 3 < VV);
  if (cfull) {
    xc = *(const f32x4*)(grow + vc);
  } else {
#pragma unroll
    for (int j = 0; j < 4; ++j) xc[j] = (vc + j < VV) ? grow[vc + j] : FNEG;
  }

  // ---- scan: max + top4 (branch-free inserts, guarded for OOB) ----
  float m = FNEG;
  L4 top; l4_init(top);
#pragma unroll
  for (int j = 0; j < 4; ++j) { float x = xa[j]; if (x > m) m = x; l4_insert(top, x, va + j); }
#pragma unroll
  for (int j = 0; j < 4; ++j) { float x = xb[j]; if (x > m) m = x; l4_insert(top, x, vb + j); }
#pragma unroll
  for (int j = 0; j < 4; ++j) {
    if (vc + j < VV) { float x = xc[j]; if (x > m) m = x; l4_insert(top, x, vc + j); }
  }

  // intra-wave reduce (64 lanes, butterfly; distinct indices -> exact)
  for (int off = 32; off; off >>= 1) {
    float m2 = __shfl_xor(m, off);
    if (m2 > m) m = m2;
    L4 o = l4_shfl_xor(top, off);
    l4_merge(top, o);
  }
  if (lane == 0) {
    wmax[wid] = m;
    wv4[wid * 4 + 0] = top.v0; wi4[wid * 4 + 0] = top.i0;
    wv4[wid * 4 + 1] = top.v1; wi4[wid * 4 + 1] = top.i1;
    wv4[wid * 4 + 2] = top.v2; wi4[wid * 4 + 2] = top.i2;
    wv4[wid * 4 + 3] = top.v3; wi4[wid * 4 + 3] = top.i3;
  }
  __syncthreads();                                        // barrier #1

  // every wave redundantly merges the 16 partial maxima -> gm in all lanes
  float mm = wmax[lane & 15];
#pragma unroll
  for (int off = 8; off; off >>= 1) {
    float m2 = __shfl_xor(mm, off);
    if (m2 > mm) mm = m2;
  }
  const float gm = mm;

  // wave 0 additionally merges the 16 top4 partials (result in lane 0 = t 0)
  L4 aa; l4_init(aa);
  if (wid == 0) {
    const int g = lane & 15;
    aa.v0 = wv4[g * 4 + 0]; aa.i0 = wi4[g * 4 + 0];
    aa.v1 = wv4[g * 4 + 1]; aa.i1 = wi4[g * 4 + 1];
    aa.v2 = wv4[g * 4 + 2]; aa.i2 = wi4[g * 4 + 2];
    aa.v3 = wv4[g * 4 + 3]; aa.i3 = wi4[g * 4 + 3];
#pragma unroll
    for (int off = 8; off; off >>= 1) {
      L4 o = l4_shfl_xor(aa, off);
      l4_merge(aa, o);
    }
  }

  // exp pass: f32 sub, double exp, store f32 (identical values per v)
  {
    f32x4 ea, eb;
#pragma unroll
    for (int j = 0; j < 4; ++j) ea[j] = (float)exp((double)(xa[j] - gm));
#pragma unroll
    for (int j = 0; j < 4; ++j) eb[j] = (float)exp((double)(xb[j] - gm));
    *(f32x4*)(row + va) = ea;      // ds_write_b128, 16B aligned
    *(f32x4*)(row + vb) = eb;
    if (cfull) {
      f32x4 ec;
#pragma unroll
      for (int j = 0; j < 4; ++j) ec[j] = (float)exp((double)(xc[j] - gm));
      *(f32x4*)(row + vc) = ec;
    } else {
#pragma unroll
      for (int j = 0; j < 4; ++j)
        if (vc + j < VV) row[vc + j] = (float)exp((double)(xc[j] - gm));
    }
  }
  __syncthreads();                                        // barrier #2

  // ---- 128 leaf sums, residue-parallel: group g = t>>3, lane j = t&7 ----
  {
    const int g = t >> 3, j = t & 7;
    int base = 0, nn = VV;
#pragma unroll
    for (int k = 6; k >= 0; --k) {           // descend to leaf (node 127+g)
      int half = nn >> 1;
      int n2 = half - (half & 7);
      if ((g >> k) & 1) { base += n2; nn -= n2; } else nn = n2;
    }
    const float* a = row + base;
    const int full = nn & ~7;
    float r = a[j];                           // indices j, j+8, ... ascending
    for (int i = 8 + j; i < full; i += 8) r += a[i];
    float s = r + __shfl_xor(r, 1);           // (r0+r1),(r2+r3),...
    s = s + __shfl_xor(s, 2);                 // (r0+r1)+(r2+r3), ...
    s = s + __shfl_xor(s, 4);                 // full 8-acc combine (np order)
    if (j == 0) {
      for (int i = full; i < nn; ++i) s += a[i];   // serial tail, np order
      leafS[g] = s;
    }
  }
  __syncthreads();                                        // barrier #3

  // ---- combine tree, single wave (HW-verified bit-exact pairing) ----
  if (t < 64) {
    float v = leafS[2 * t] + leafS[2 * t + 1];         // node 63+t
#pragma unroll
    for (int l = 0; l < 6; ++l) {                      // v(q) <- v(2q)+v(2q+1)
      float x0 = __shfl(v, t * 2);
      float x1 = __shfl(v, t * 2 + 1);
      v = x0 + x1;
    }
    if (t == 0) {
      float ls = (float)log((double)v);
      topP[n * 4 + 0] = (aa.v0 - gm) - ls;  topI[n * 4 + 0] = aa.i0;
      topP[n * 4 + 1] = (aa.v1 - gm) - ls;  topI[n * 4 + 1] = aa.i1;
      topP[n * 4 + 2] = (aa.v2 - gm) - ls;  topI[n * 4 + 2] = aa.i2;
      topP[n * 4 + 3] = (aa.v3 - gm) - ls;  topI[n * 4 + 3] = aa.i3;
    }
  }
}

// ---------- kernel 3: finalize + fused beam(14) j=0 argmax ----------
__global__ __launch_bounds__(64)
void k_final(const int* __restrict__ chainIn, const float* __restrict__ probIn,
             const float* __restrict__ topP, const int* __restrict__ topI,
             const float* __restrict__ E,
             const float* __restrict__ Wc, const float* __restrict__ bc,
             const float* __restrict__ Wt, const float* __restrict__ zt,
             const float* __restrict__ Wzt, float* __restrict__ out) {
  int blk = blockIdx.x;           // 224 = B*(T-2)
  int b = blk / (TT - 2), tpos = blk % (TT - 2);
  int lane = threadIdx.x;         // 64 = C

  // beam(14) j=0: argmax over 32 candidates (M=8), exact replica of the
  // first iteration of the k_beam shfl network; both 32-lane halves compute
  // identically, so src is wave-uniform.
  const int c = lane & 31;
  int mi = c >> 2, k = c & 3;
  float act = probIn[b * 8 + mi] * topP[(b * 8 + mi) * 4 + k];
  float rv = act; int ri = c;
#pragma unroll
  for (int off = 1; off < 32; off <<= 1) {
    float v2 = __shfl_xor(rv, off, 32);
    int   i2 = __shfl_xor(ri, off, 32);
    if (v2 > rv || (v2 == rv && i2 < ri)) { rv = v2; ri = i2; }
  }
  const int src = b * 8 + (ri >> 2);        // best beam's source row
  // positions 1..14 all come from chainIn (q = step+1 = 15 is never read)
  int loc = chainIn[src * TT + 1 + tpos];
  if ((unsigned)loc >= VV) loc = 0;        // defensive

  double acc = (double)bc[lane];
  const float* er = E + loc * DD;
  for (int d = 0; d < DD; ++d) acc += (double)er[d] * (double)Wc[d * CC + lane];
  double val = tanh(acc) * (double)Wt[lane];
  const float* ztr = zt + b * DD;
#pragma unroll
  for (int q = 0; q < 4; ++q) val += (double)ztr[lane * 4 + q] * (double)Wzt[lane * 4 + q];
  for (int off = 32; off; off >>= 1) val += __shfl_down(val, off);
  if (lane == 0) {
    out[b * (TT - 2) + tpos] = (float)loc;                 // loc_chain as float
    out[BB * (TT - 2) + b * (TT - 2) + tpos] = (float)val; // tim_chain
  }
}

// ---------- host ----------
extern "C" void kernel_launch(void* const* d_in, const int* in_sizes, int n_in,
                              void* d_out, int out_size, void* d_ws, size_t ws_size,
                              hipStream_t stream) {
  const int*   loc_tar = (const int*)  d_in[0];
  const float* zs      = (const float*)d_in[1];
  const float* zt      = (const float*)d_in[2];
  const float* E       = (const float*)d_in[3];
  const float* Wv      = (const float*)d_in[4];
  const float* bv      = (const float*)d_in[5];
  const float* Wc      = (const float*)d_in[6];
  const float* bc      = (const float*)d_in[7];
  const float* Wt      = (const float*)d_in[8];
  const float* Wzt     = (const float*)d_in[9];
  float* out = (float*)d_out;

  char* w = (char*)d_ws;
  float* Lg     = (float*)(w);                   // 128*10016*4 = 5,128,192 B
  float* topP   = (float*)(w + 5128192);         // 512 f32
  int*   topI   = (int*)  (w + 5130240);         // 512 int
  float* probA  = (float*)(w + 5132288);         // 128 f32
  float* probB  = (float*)(w + 5132800);         // 128 f32
  int*   chainA = (int*)  (w + 5133312);         // 2048 int
  int*   chainB = (int*)  (w + 5141504);         // 2048 int

  float* pIn = probA; float* pOut = probB;
  int*   cIn = chainA; int*  cOut = chainB;

  // step 0: N=16 (beam state unused; tokens direct from loc_tar)
  k_gemm<<<(16 / RPB) * NVT, 256, 0, stream>>>(E, zs, Wv, bv, loc_tar,
      topP, topI, pIn, cIn, pOut, cOut, Lg, 0, 16, 0);
  k_red<<<16, 1024, 0, stream>>>(Lg, topP, topI);

  for (int i = 1; i < TT - 1; ++i) {
    int N = (i == 1) ? (BB * KK) : (BB * 2 * KK);
    int Mshift = (i == 1) ? 2 : 3;
    k_gemm<<<(N / RPB) * NVT, 256, 0, stream>>>(E, zs, Wv, bv, loc_tar,
        topP, topI, pIn, cIn, pOut, cOut, Lg, i, N, Mshift);
    k_red<<<N, 1024, 0, stream>>>(Lg, topP, topI);
    float* pt = pIn; pIn = pOut; pOut = pt;
    int*   ct = cIn; cIn = cOut; cOut = ct;
  }

  // k_final recomputes beam(14)'s j=0 selection from (probIn, topP, topI)
  k_final<<<BB * (TT - 2), 64, 0, stream>>>(cIn, pIn, topP, topI,
                                            E, Wc, bc, Wt, zt, Wzt, out);
}